// Round 5
// baseline (667.622 us; speedup 1.0000x reference)
//
#include <hip/hip_runtime.h>
#include <hip/hip_bf16.h>
#include <math.h>

#define F_IN 512
#define HID  16
#define C_OUT 40

#define BSH    7            // 128 nodes per coarse bucket
#define BNODES 128
#define MAXNB  1024         // N=100000 -> NB=782

#define EPB 8192            // edges per block in count/partition
#define CTH 512

__device__ __forceinline__ unsigned short f2bf(float f) {
    unsigned u = __float_as_uint(f);
    unsigned r = (u + 0x7FFF + ((u >> 16) & 1)) >> 16;   // RNE
    return (unsigned short)r;
}
__device__ __forceinline__ float bf2f(unsigned short h) {
    return __uint_as_float(((unsigned)h) << 16);
}
// 15-bit sign-less bf16 (ew >= 0 always), RNE
__device__ __forceinline__ unsigned ew15(unsigned u) {
    return ((u + 0x7FFF + ((u >> 16) & 1)) >> 16) & 0x7FFF;
}

// ---------------------------------------------------------------------------
// K0: zero global bucket counters
// ---------------------------------------------------------------------------
__global__ __launch_bounds__(1024) void k_zero(int* __restrict__ g, int n) {
    int t = threadIdx.x;
    if (t < n) g[t] = 0;
}

// ---------------------------------------------------------------------------
// K1: coarse bucket histogram; stores per-block histogram row + global counts
// ---------------------------------------------------------------------------
__global__ __launch_bounds__(CTH) void k_count(const int* __restrict__ col,
                                               int* __restrict__ bh,
                                               int* __restrict__ gcnt,
                                               int E, int NB) {
    __shared__ int lc[MAXNB];
    int t = threadIdx.x;
    for (int i = t; i < NB; i += CTH) lc[i] = 0;
    __syncthreads();
    int base = blockIdx.x * EPB;
#pragma unroll
    for (int i = 0; i < EPB / CTH; ++i) {
        int e = base + t + i * CTH;
        if (e < E) atomicAdd(&lc[col[e] >> BSH], 1);
    }
    __syncthreads();
    int* bhrow = bh + (size_t)blockIdx.x * MAXNB;
    for (int i = t; i < NB; i += CTH) {
        int c = lc[i];
        bhrow[i] = c;
        if (c) atomicAdd(&gcnt[i], c);
    }
}

// ---------------------------------------------------------------------------
// K2: exclusive scan of bucket counts -> bo; sentinels
// ---------------------------------------------------------------------------
__global__ __launch_bounds__(1024) void k_scan(const int* __restrict__ gcnt,
                                               int* __restrict__ bo,
                                               int* __restrict__ offs,
                                               int NB, int N, int E) {
    __shared__ int s[1024];
    int t = threadIdx.x;
    int v = (t < NB) ? gcnt[t] : 0;
    s[t] = v;
    __syncthreads();
    for (int off = 1; off < 1024; off <<= 1) {
        int x = (t >= off) ? s[t - off] : 0;
        __syncthreads();
        s[t] += x;
        __syncthreads();
    }
    if (t < NB) bo[t] = s[t] - v;
    if (t == 0) { bo[NB] = E; offs[N] = E; }
}

// ---------------------------------------------------------------------------
// K2b: per-(block,bucket) placement bases: bb[blk][b] = bo[b] + prefix(bh)
// ---------------------------------------------------------------------------
__global__ __launch_bounds__(128) void k_scan2(const int* __restrict__ bo,
                                               const int* __restrict__ bh,
                                               int* __restrict__ bb,
                                               int NB, int NBLK) {
    int t = blockIdx.x * 128 + threadIdx.x;
    if (t >= NB) return;
    int base = bo[t];
    for (int blk = 0; blk < NBLK; ++blk) {
        bb[(size_t)blk * MAXNB + t] = base;
        base += bh[(size_t)blk * MAXNB + t];
    }
}

// ---------------------------------------------------------------------------
// K3: placement — single pass, deterministic bases, LDS rank counters
// record .x=(row<<7)|col_low, .y=ew f32 bits
// ---------------------------------------------------------------------------
__global__ __launch_bounds__(CTH) void k_part(const int* __restrict__ row,
                                              const int* __restrict__ col,
                                              const float* __restrict__ ew,
                                              const int* __restrict__ bb,
                                              int2* __restrict__ st,
                                              int E, int NB) {
    __shared__ int lc[MAXNB];
    __shared__ int lb[MAXNB];
    int t = threadIdx.x;
    const int* bbrow = bb + (size_t)blockIdx.x * MAXNB;
    for (int i = t; i < NB; i += CTH) { lc[i] = 0; lb[i] = bbrow[i]; }
    __syncthreads();
    int base = blockIdx.x * EPB;
#pragma unroll
    for (int i = 0; i < EPB / CTH; ++i) {
        int e = base + t + i * CTH;
        if (e < E) {
            int c = col[e];
            int b = c >> BSH;
            int r = atomicAdd(&lc[b], 1);
            st[lb[b] + r] = make_int2((row[e] << BSH) | (c & (BNODES - 1)),
                                      __float_as_int(ew[e]));
        }
    }
}

// ---------------------------------------------------------------------------
// K4: per-bucket counting sort -> packed u32 records (row<<15 | ew15),
// per-node offs, dinv = rsqrt(1 + sum ew)
// ---------------------------------------------------------------------------
__global__ __launch_bounds__(256) void k_sort(const int* __restrict__ bo,
                                              const int2* __restrict__ st,
                                              unsigned* __restrict__ st2,
                                              int* __restrict__ offs,
                                              float* __restrict__ dinv, int N) {
    __shared__ int cnt[BNODES];
    __shared__ float wsum[BNODES];
    __shared__ int off[BNODES];
    int t = threadIdx.x;
    int b = blockIdx.x;
    if (t < BNODES) { cnt[t] = 0; wsum[t] = 0.0f; }
    __syncthreads();
    int beg = bo[b], end = bo[b + 1];
    for (int e = beg + t; e < end; e += 256) {
        int2 rec = st[e];
        int cl = rec.x & (BNODES - 1);
        atomicAdd(&cnt[cl], 1);
        atomicAdd(&wsum[cl], __int_as_float(rec.y));
    }
    __syncthreads();
    if (t < BNODES) off[t] = cnt[t];
    __syncthreads();
    for (int o = 1; o < BNODES; o <<= 1) {
        int v = (t < BNODES && t >= o) ? off[t - o] : 0;
        __syncthreads();
        if (t < BNODES) off[t] += v;
        __syncthreads();
    }
    if (t < BNODES) {
        int ex = off[t] - cnt[t];
        off[t] = ex;
        int n = b * BNODES + t;
        if (n < N) {
            offs[n] = beg + ex;
            dinv[n] = rsqrtf(1.0f + wsum[t]);
        }
        cnt[t] = 0;
    }
    __syncthreads();
    for (int e = beg + t; e < end; e += 256) {
        int2 rec = st[e];
        int cl = rec.x & (BNODES - 1);
        int r = atomicAdd(&cnt[cl], 1);
        st2[beg + off[cl] + r] =
            ((unsigned)(rec.x >> BSH) << 15) | ew15((unsigned)rec.y);
    }
}

// ---------------------------------------------------------------------------
// K5: h1' = dinv * (x @ W1), bf16 out. Split-K: 4 waves x 64 nodes/block.
// Wave w owns K in [w*128, w*128+128); W address wave-uniform -> scalar loads.
// ---------------------------------------------------------------------------
__global__ __launch_bounds__(256) void k_gemm1(const float* __restrict__ x,
                                               const float* __restrict__ W,
                                               const float* __restrict__ dinv,
                                               unsigned short* __restrict__ hb,
                                               int N) {
    __shared__ float red[64 * 17];
    int t = threadIdx.x;
    int lane = t & 63;
    int w = t >> 6;
    int n0 = blockIdx.x * 64;
    int n = n0 + lane;
    for (int i = t; i < 64 * 17; i += 256) red[i] = 0.0f;
    __syncthreads();

    float acc[HID];
#pragma unroll
    for (int j = 0; j < HID; ++j) acc[j] = 0.0f;

    int wk0 = __builtin_amdgcn_readfirstlane(w) * 128;   // uniform K base
    bool valid = (n < N);
    int nsafe = valid ? n : (N - 1);
    const float4* xr = (const float4*)(x + (size_t)nsafe * F_IN + wk0);

    for (int it = 0; it < 4; ++it) {
        float4 xv[8];
#pragma unroll
        for (int j = 0; j < 8; ++j) xv[j] = xr[it * 8 + j];
#pragma unroll
        for (int j = 0; j < 8; ++j) {
            const float* wkp = W + (size_t)(wk0 + it * 32 + j * 4) * HID;
#pragma unroll
            for (int d = 0; d < HID; ++d) acc[d] += xv[j].x * wkp[d];
#pragma unroll
            for (int d = 0; d < HID; ++d) acc[d] += xv[j].y * wkp[HID + d];
#pragma unroll
            for (int d = 0; d < HID; ++d) acc[d] += xv[j].z * wkp[2 * HID + d];
#pragma unroll
            for (int d = 0; d < HID; ++d) acc[d] += xv[j].w * wkp[3 * HID + d];
        }
    }
    if (valid) {
#pragma unroll
        for (int d = 0; d < HID; ++d) atomicAdd(&red[lane * 17 + d], acc[d]);
    }
    __syncthreads();

    int nn = t >> 2, q = t & 3;
    int ng = n0 + nn;
    if (ng < N) {
        float dv = dinv[ng];
        const float* rp = red + nn * 17 + q * 4;
        ((ushort4*)(hb + (size_t)ng * HID + q * 4))[0] =
            make_ushort4(f2bf(dv * rp[0]), f2bf(dv * rp[1]),
                         f2bf(dv * rp[2]), f2bf(dv * rp[3]));
    }
}

// ---------------------------------------------------------------------------
// K6: layer-1 aggregate. Wave per node; lane = 4*i+q.
// ---------------------------------------------------------------------------
__global__ __launch_bounds__(256) void k_agg1(const int* __restrict__ offs,
                                              const unsigned* __restrict__ st2,
                                              const float* __restrict__ dinv,
                                              const unsigned short* __restrict__ srcb,
                                              const float* __restrict__ bias,
                                              unsigned short* __restrict__ dstb,
                                              int N) {
    int t = threadIdx.x;
    int lane = t & 63, w = t >> 6;
    int n = blockIdx.x * 4 + w;
    if (n >= N) return;
    int q = lane & 3, i = lane >> 2;
    int beg = offs[n], end = offs[n + 1];
    float4 acc = make_float4(0.f, 0.f, 0.f, 0.f);
    for (int e = beg + i; e < end; e += 16) {
        unsigned rec = st2[e];
        float wt = __uint_as_float((rec & 0x7FFFu) << 16);
        ushort4 v = ((const ushort4*)(srcb + (size_t)(rec >> 15) * HID))[q];
        acc.x += wt * bf2f(v.x);
        acc.y += wt * bf2f(v.y);
        acc.z += wt * bf2f(v.z);
        acc.w += wt * bf2f(v.w);
    }
#pragma unroll
    for (int off = 4; off < 64; off <<= 1) {
        acc.x += __shfl_xor(acc.x, off, 64);
        acc.y += __shfl_xor(acc.y, off, 64);
        acc.z += __shfl_xor(acc.z, off, 64);
        acc.w += __shfl_xor(acc.w, off, 64);
    }
    if (i == 0) {
        float d = dinv[n];
        ushort4 sv = ((const ushort4*)(srcb + (size_t)n * HID))[q];
        float4 bq = ((const float4*)bias)[q];
        float r0 = d * fmaxf(d * (acc.x + bf2f(sv.x)) + bq.x, 0.f);
        float r1 = d * fmaxf(d * (acc.y + bf2f(sv.y)) + bq.y, 0.f);
        float r2 = d * fmaxf(d * (acc.z + bf2f(sv.z)) + bq.z, 0.f);
        float r3 = d * fmaxf(d * (acc.w + bf2f(sv.w)) + bq.w, 0.f);
        ((ushort4*)(dstb + (size_t)n * HID))[q] =
            make_ushort4(f2bf(r0), f2bf(r1), f2bf(r2), f2bf(r3));
    }
}

// ---------------------------------------------------------------------------
// K7: layer-2 aggregate fused with W2 matvec + bias + log_softmax.
// ---------------------------------------------------------------------------
__global__ __launch_bounds__(256) void k_agg2(const int* __restrict__ offs,
                                              const unsigned* __restrict__ st2,
                                              const float* __restrict__ dinv,
                                              const unsigned short* __restrict__ srcb,
                                              const float* __restrict__ W2,
                                              const float* __restrict__ b2,
                                              float* __restrict__ out, int N) {
    __shared__ float Ws[HID * C_OUT];
    __shared__ float bs[C_OUT];
    int t = threadIdx.x;
    for (int iw = t; iw < HID * C_OUT; iw += 256) Ws[iw] = W2[iw];
    if (t < C_OUT) bs[t] = b2[t];
    __syncthreads();

    int lane = t & 63, w = t >> 6;
    int n = blockIdx.x * 4 + w;
    if (n >= N) return;
    int q = lane & 3, i = lane >> 2;
    int beg = offs[n], end = offs[n + 1];
    float4 acc = make_float4(0.f, 0.f, 0.f, 0.f);
    for (int e = beg + i; e < end; e += 16) {
        unsigned rec = st2[e];
        float wt = __uint_as_float((rec & 0x7FFFu) << 16);
        ushort4 v = ((const ushort4*)(srcb + (size_t)(rec >> 15) * HID))[q];
        acc.x += wt * bf2f(v.x);
        acc.y += wt * bf2f(v.y);
        acc.z += wt * bf2f(v.z);
        acc.w += wt * bf2f(v.w);
    }
#pragma unroll
    for (int off = 4; off < 64; off <<= 1) {
        acc.x += __shfl_xor(acc.x, off, 64);
        acc.y += __shfl_xor(acc.y, off, 64);
        acc.z += __shfl_xor(acc.z, off, 64);
        acc.w += __shfl_xor(acc.w, off, 64);
    }
    float d = dinv[n];
    ushort4 sv = ((const ushort4*)(srcb + (size_t)n * HID))[q];
    float gq[4];
    gq[0] = d * (acc.x + bf2f(sv.x));
    gq[1] = d * (acc.y + bf2f(sv.y));
    gq[2] = d * (acc.z + bf2f(sv.z));
    gq[3] = d * (acc.w + bf2f(sv.w));
    float g16[16];
    int base = lane & ~3;
#pragma unroll
    for (int qq = 0; qq < 4; ++qq) {
#pragma unroll
        for (int k = 0; k < 4; ++k)
            g16[qq * 4 + k] = __shfl(gq[k], base + qq, 64);
    }
    float logit = -INFINITY;
    if (lane < C_OUT) {
        float a = bs[lane];
#pragma unroll
        for (int j = 0; j < HID; ++j) a += g16[j] * Ws[j * C_OUT + lane];
        logit = a;
    }
    float m = logit;
#pragma unroll
    for (int off = 32; off > 0; off >>= 1) m = fmaxf(m, __shfl_xor(m, off, 64));
    float ex = (lane < C_OUT) ? __expf(logit - m) : 0.0f;
    float s = ex;
#pragma unroll
    for (int off = 32; off > 0; off >>= 1) s += __shfl_xor(s, off, 64);
    if (lane < C_OUT) out[(size_t)n * C_OUT + lane] = logit - m - __logf(s);
}

// ---------------------------------------------------------------------------
extern "C" void kernel_launch(void* const* d_in, const int* in_sizes, int n_in,
                              void* d_out, int out_size, void* d_ws, size_t ws_size,
                              hipStream_t stream) {
    const float* x   = (const float*)d_in[0];
    const int*   ei  = (const int*)d_in[1];
    const float* ew  = (const float*)d_in[2];
    const float* W1  = (const float*)d_in[3];
    const float* b1  = (const float*)d_in[4];
    const float* W2  = (const float*)d_in[5];
    const float* b2  = (const float*)d_in[6];
    float* out = (float*)d_out;

    const int N = in_sizes[0] / F_IN;          // 100000
    const int E = in_sizes[2];                 // 3200000
    const int* row = ei;
    const int* col = ei + E;
    const int NB = (N + BNODES - 1) >> BSH;    // 782
    const int gC = (E + EPB - 1) / EPB;        // 391

    // workspace carve (4-byte words)
    int* wsi = (int*)d_ws;
    size_t o = 0;
    int* gcnt  = wsi + o; o += MAXNB;
    int* bo    = wsi + o; o += MAXNB + 1;
    int* offs  = wsi + o; o += (size_t)N + 8;
    float* dinv = (float*)(wsi + o); o += N;
    unsigned short* h1b = (unsigned short*)(wsi + o); o += (size_t)N * HID / 2;
    unsigned short* a1b = (unsigned short*)(wsi + o); o += (size_t)N * HID / 2;
    int* bh    = wsi + o; o += (size_t)gC * MAXNB;
    int* bb    = wsi + o; o += (size_t)gC * MAXNB;
    int2* st   = (int2*)(wsi + o); o += (size_t)E * 2;
    unsigned* st2 = (unsigned*)(wsi + o); o += (size_t)E;

    int gW = (N + 3) / 4;                      // 25000

    k_zero<<<1, 1024, 0, stream>>>(gcnt, NB);
    k_count<<<gC, CTH, 0, stream>>>(col, bh, gcnt, E, NB);
    k_scan<<<1, 1024, 0, stream>>>(gcnt, bo, offs, NB, N, E);
    k_scan2<<<(NB + 127) / 128, 128, 0, stream>>>(bo, bh, bb, NB, gC);
    k_part<<<gC, CTH, 0, stream>>>(row, col, ew, bb, st, E, NB);
    k_sort<<<NB, 256, 0, stream>>>(bo, st, st2, offs, dinv, N);
    k_gemm1<<<(N + 63) / 64, 256, 0, stream>>>(x, W1, dinv, h1b, N);
    k_agg1<<<gW, 256, 0, stream>>>(offs, st2, dinv, h1b, b1, a1b, N);
    k_agg2<<<gW, 256, 0, stream>>>(offs, st2, dinv, a1b, W2, b2, out, N);
}